// Round 3
// baseline (215.409 us; speedup 1.0000x reference)
//
#include <hip/hip_runtime.h>
#include <hip/hip_bf16.h>
#include <cstddef>
#include <cstdint>

// Problem constants: B=2, C=128, N=32768, K=9, H=512
#define BB 2
#define CC 128
#define NN 32768
#define KNBR 9
#define HH 512
#define PP (BB * NN)          // 65536 points
#define TWO_C 256
#define EPSBN 1e-5f

typedef __attribute__((ext_vector_type(4))) float f32x4;
typedef __attribute__((ext_vector_type(8))) short s16x8;

__device__ __forceinline__ float bf2f(unsigned int u) {
    return __uint_as_float(u << 16);
}
__device__ __forceinline__ unsigned short f2bf(float f) {
    unsigned int u = __float_as_uint(f);
    u += 0x7fffu + ((u >> 16) & 1u);   // RNE
    return (unsigned short)(u >> 16);
}

// ---------------------------------------------------------------------------
// x [B, C, N] fp32 -> xT [B*N, C] bf16
__global__ __launch_bounds__(256) void transpose_kernel(
    const float* __restrict__ x, unsigned short* __restrict__ xT) {
    __shared__ float t[32][129];
    const int b = blockIdx.y;
    const int n0 = blockIdx.x * 32;
    const int tid = threadIdx.x;
    {
        const int tn = tid % 32;
        const int cq = tid / 32;
        for (int c = cq; c < CC; c += 8)
            t[tn][c] = x[((size_t)b * CC + c) * NN + n0 + tn];
    }
    __syncthreads();
    {
        const int ct = tid % 128;
        const int nq = tid / 128;
        for (int nl = nq; nl < 32; nl += 2)
            xT[((size_t)b * NN + n0 + nl) * CC + ct] = f2bf(t[nl][ct]);
    }
}

// ---------------------------------------------------------------------------
// Gather + max-relative; featT[p][2c]=x[p][c], featT[p][2c+1]=max_k(x_j-x_i).
__global__ __launch_bounds__(256) void gather_kernel(
    const unsigned short* __restrict__ xT, const int* __restrict__ ei,
    unsigned short* __restrict__ featT) {
    const int pt = blockIdx.x * 4 + (threadIdx.x >> 6);
    const int lane = threadIdx.x & 63;
    const int b = pt >> 15;
    const int n = pt & (NN - 1);
    const unsigned short* xb = xT + (size_t)b * NN * CC;
    const int* e0 = ei + ((size_t)b * NN + n) * KNBR;            // edge_index[0]: x_j
    const int* e1 = ei + ((size_t)(BB + b) * NN + n) * KNBR;     // edge_index[1]: x_i

    const unsigned int xv = *(const unsigned int*)(xb + (size_t)n * CC + lane * 2);
    float m0 = -INFINITY, m1 = -INFINITY;
#pragma unroll
    for (int k = 0; k < KNBR; k++) {
        const int j0 = e0[k], j1 = e1[k];
        const unsigned int va = *(const unsigned int*)(xb + (size_t)j0 * CC + lane * 2);
        const unsigned int vb = *(const unsigned int*)(xb + (size_t)j1 * CC + lane * 2);
        m0 = fmaxf(m0, bf2f(va & 0xffffu) - bf2f(vb & 0xffffu));
        m1 = fmaxf(m1, bf2f(va >> 16) - bf2f(vb >> 16));
    }
    ushort4 o;
    o.x = (unsigned short)(xv & 0xffffu);
    o.y = f2bf(m0);
    o.z = (unsigned short)(xv >> 16);
    o.w = f2bf(m1);
    *(ushort4*)(featT + (size_t)pt * TWO_C + lane * 4) = o;
}

// ---------------------------------------------------------------------------
// fp32 weights -> bf16
__global__ __launch_bounds__(256) void wconv_kernel(
    const float* __restrict__ w_mr, const float* __restrict__ w1,
    const float* __restrict__ w2, unsigned short* __restrict__ o_mr,
    unsigned short* __restrict__ o1, unsigned short* __restrict__ o2) {
    const int i = blockIdx.x * 256 + threadIdx.x;
    if (i < CC * TWO_C) o_mr[i] = f2bf(w_mr[i]);
    o1[i] = f2bf(w1[i]);
    o2[i] = f2bf(w2[i]);
}

// ---------------------------------------------------------------------------
// Direct-fragment bf16 MFMA GEMM (no LDS staging, no main-loop barriers).
// Cout[p,o] = sum_k actA(A[p,k]) * W[o,k] + bias[o]
//   actA(v) = ACT ? bf16(relu(a[k]*v + b[k])) : v
// Both A [P,KTOT] and W [OC,KTOT] are row-major along K, so each MFMA
// fragment (8 consecutive k at one row) is a contiguous 16B global load.
// Tile 128x128 per block, 4 waves (2x2 of 64x64), K-step 32.
// Per-channel sum/sumsq of (acc+bias) fused into epilogue -> stats[2*OC].
template <int KTOT, int OC, bool ACT>
__global__ __launch_bounds__(256) void dgemm_kernel(
    const unsigned short* __restrict__ A,
    const unsigned short* __restrict__ W,
    const float* __restrict__ bias,
    const float* __restrict__ act,      // [2*KTOT]: a then b
    unsigned short* __restrict__ Cout,
    float* __restrict__ stats) {
    __shared__ float bsA[256];
    __shared__ float bsB[256];

    const int tid = threadIdx.x;
    const int pb = blockIdx.x * 128;
    const int ob = blockIdx.y * 128;
    const int w = tid >> 6;
    const int wr = w >> 1, wc = w & 1;
    const int lane = tid & 63;
    const int lm = lane & 15, lg = lane >> 4;

    const unsigned short* Ab = A + (size_t)(pb + wr * 64 + lm) * KTOT + lg * 8;
    const unsigned short* Wb = W + (size_t)(ob + wc * 64 + lm) * KTOT + lg * 8;

    f32x4 acc[4][4] = {};

    for (int k0 = 0; k0 < KTOT; k0 += 32) {
        s16x8 aF[4], bF[4];
        f32x4 sa0, sa1, sb0, sb1;
        if (ACT) {
            const int ke = k0 + lg * 8;
            sa0 = *(const f32x4*)(act + ke);
            sa1 = *(const f32x4*)(act + ke + 4);
            sb0 = *(const f32x4*)(act + KTOT + ke);
            sb1 = *(const f32x4*)(act + KTOT + ke + 4);
        }
#pragma unroll
        for (int n = 0; n < 4; n++)
            bF[n] = *(const s16x8*)(Wb + (size_t)n * 16 * KTOT + k0);
#pragma unroll
        for (int m = 0; m < 4; m++) {
            s16x8 v = *(const s16x8*)(Ab + (size_t)m * 16 * KTOT + k0);
            if (ACT) {
                s16x8 r;
#pragma unroll
                for (int j = 0; j < 4; j++)
                    r[j] = (short)f2bf(
                        fmaxf(fmaf(sa0[j], bf2f((unsigned short)v[j]), sb0[j]), 0.f));
#pragma unroll
                for (int j = 0; j < 4; j++)
                    r[4 + j] = (short)f2bf(
                        fmaxf(fmaf(sa1[j], bf2f((unsigned short)v[4 + j]), sb1[j]), 0.f));
                v = r;
            }
            aF[m] = v;
        }
#pragma unroll
        for (int m = 0; m < 4; m++)
#pragma unroll
            for (int n = 0; n < 4; n++)
                acc[m][n] = __builtin_amdgcn_mfma_f32_16x16x32_bf16(
                    aF[m], bF[n], acc[m][n], 0, 0, 0);
    }

    // ---- epilogue: bias, bf16 store, fused per-channel stats ----
    float sA[4] = {0.f, 0.f, 0.f, 0.f};
    float sB[4] = {0.f, 0.f, 0.f, 0.f};
#pragma unroll
    for (int n = 0; n < 4; n++) {
        const int o = ob + wc * 64 + n * 16 + lm;
        const float bo = bias[o];
#pragma unroll
        for (int m = 0; m < 4; m++) {
            const size_t p = (size_t)pb + wr * 64 + m * 16 + lg * 4;
#pragma unroll
            for (int j = 0; j < 4; j++) {
                const float h = acc[m][n][j] + bo;
                Cout[(p + j) * OC + o] = f2bf(h);
                sA[n] += h;
                sB[n] = fmaf(h, h, sB[n]);
            }
        }
    }
#pragma unroll
    for (int n = 0; n < 4; n++) {
        float a = sA[n], q = sB[n];
        a += __shfl_xor(a, 16); a += __shfl_xor(a, 32);
        q += __shfl_xor(q, 16); q += __shfl_xor(q, 32);
        if (lg == 0) {
            bsA[wr * 128 + wc * 64 + n * 16 + lm] = a;
            bsB[wr * 128 + wc * 64 + n * 16 + lm] = q;
        }
    }
    __syncthreads();
    if (tid < 128) {
        atomicAdd(&stats[ob + tid], bsA[tid] + bsA[128 + tid]);
        atomicAdd(&stats[OC + ob + tid], bsB[tid] + bsB[128 + tid]);
    }
}

// ---------------------------------------------------------------------------
// stats -> per-channel affine (a, b): bn(v) = a*v + b
__global__ void finalize_kernel(const float* __restrict__ stats,
                                const float* __restrict__ g,
                                const float* __restrict__ be,
                                float* __restrict__ act, int CH, float invP) {
    const int c = blockIdx.x * blockDim.x + threadIdx.x;
    if (c < CH) {
        const float mean = stats[c] * invP;
        const float var = stats[CH + c] * invP - mean * mean;
        const float a = g[c] * rsqrtf(var + EPSBN);
        act[c] = a;
        act[CH + c] = be[c] - mean * a;
    }
}

// ---------------------------------------------------------------------------
// out[b,c,n] = a3[c]*o[p,c] + b3[c] + relu(a1[c]*y[p,c] + b1[c]); [p,C]->[B,C,N]
__global__ __launch_bounds__(256) void final_kernel(
    const unsigned short* __restrict__ y_bf, const unsigned short* __restrict__ o_bf,
    const float* __restrict__ act1, const float* __restrict__ act3,
    float* __restrict__ out) {
    __shared__ float t[32][129];
    const int b = blockIdx.y;
    const int n0 = blockIdx.x * 32;
    const int tid = threadIdx.x;
    {
        const int lane = tid & 63;
        const int rq = tid >> 6;
        const int c0 = lane * 2;
        const float a1x = act1[c0], a1y = act1[c0 + 1];
        const float b1x = act1[CC + c0], b1y = act1[CC + c0 + 1];
        const float a3x = act3[c0], a3y = act3[c0 + 1];
        const float b3x = act3[CC + c0], b3y = act3[CC + c0 + 1];
        for (int rl = rq; rl < 32; rl += 4) {
            const size_t p = (size_t)b * NN + n0 + rl;
            const unsigned int yv = *(const unsigned int*)(y_bf + p * CC + c0);
            const unsigned int ov = *(const unsigned int*)(o_bf + p * CC + c0);
            t[rl][c0]     = fmaf(a3x, bf2f(ov & 0xffffu), b3x) +
                            fmaxf(fmaf(a1x, bf2f(yv & 0xffffu), b1x), 0.f);
            t[rl][c0 + 1] = fmaf(a3y, bf2f(ov >> 16), b3y) +
                            fmaxf(fmaf(a1y, bf2f(yv >> 16), b1y), 0.f);
        }
    }
    __syncthreads();
    {
        const int tn = tid % 32;
        const int cq = tid / 32;
        for (int c = cq; c < CC; c += 8)
            out[((size_t)b * CC + c) * NN + n0 + tn] = t[tn][c];
    }
}

// ---------------------------------------------------------------------------
extern "C" void kernel_launch(void* const* d_in, const int* in_sizes, int n_in,
                              void* d_out, int out_size, void* d_ws, size_t ws_size,
                              hipStream_t stream) {
    const float* x     = (const float*)d_in[0];
    const int*   ei    = (const int*)d_in[1];
    const float* w_mr  = (const float*)d_in[2];
    const float* b_mr  = (const float*)d_in[3];
    const float* g_mr  = (const float*)d_in[4];
    const float* be_mr = (const float*)d_in[5];
    const float* w1    = (const float*)d_in[6];
    const float* b1    = (const float*)d_in[7];
    const float* g1    = (const float*)d_in[8];
    const float* be1   = (const float*)d_in[9];
    const float* w2    = (const float*)d_in[10];
    const float* b2    = (const float*)d_in[11];
    const float* g2    = (const float*)d_in[12];
    const float* be2   = (const float*)d_in[13];
    float* out = (float*)d_out;

    // workspace layout (bytes)
    char* ws = (char*)d_ws;
    unsigned short* xT    = (unsigned short*)(ws + 0);           // P*C*2   = 16 MB
    unsigned short* featT = (unsigned short*)(ws + 16777216);    // P*2C*2  = 32 MB
    unsigned short* y_bf  = (unsigned short*)(ws + 50331648);    // P*C*2   = 16 MB
    unsigned short* h_bf  = (unsigned short*)(ws + 67108864);    // P*H*2   = 64 MB
    unsigned short* o_bf  = (unsigned short*)(ws + 134217728);   // P*C*2   = 16 MB
    unsigned short* wmr_b = (unsigned short*)(ws + 150994944);   // 64 KB
    unsigned short* w1_b  = (unsigned short*)(ws + 151060480);   // 128 KB
    unsigned short* w2_b  = (unsigned short*)(ws + 151191552);   // 128 KB
    float* stats1 = (float*)(ws + 151322624);                    // 2*128
    float* stats2 = (float*)(ws + 151323648);                    // 2*512
    float* stats3 = (float*)(ws + 151327744);                    // 2*128
    float* act1   = (float*)(ws + 151328768);                    // 2*128
    float* act2   = (float*)(ws + 151329792);                    // 2*512
    float* act3   = (float*)(ws + 151333888);                    // 2*128

    const float invP = 1.0f / (float)PP;

    hipMemsetAsync(stats1, 0, 6144, stream);   // zero all three stats arrays

    transpose_kernel<<<dim3(NN / 32, BB), 256, 0, stream>>>(x, xT);
    gather_kernel<<<PP / 4, 256, 0, stream>>>(xT, ei, featT);
    wconv_kernel<<<256, 256, 0, stream>>>(w_mr, w1, w2, wmr_b, w1_b, w2_b);

    // GEMM1: feat[P,256] @ w_mr^T -> y[P,128]  (+ fused stats1)
    dgemm_kernel<TWO_C, CC, false><<<dim3(PP / 128, 1), 256, 0, stream>>>(
        featT, wmr_b, b_mr, act1, y_bf, stats1);
    finalize_kernel<<<1, CC, 0, stream>>>(stats1, g_mr, be_mr, act1, CC, invP);

    // GEMM2: relu(bn1(y))[P,128] @ w1^T -> h[P,512]  (+ fused stats2)
    dgemm_kernel<CC, HH, true><<<dim3(PP / 128, HH / 128), 256, 0, stream>>>(
        y_bf, w1_b, b1, act1, h_bf, stats2);
    finalize_kernel<<<1, HH, 0, stream>>>(stats2, g1, be1, act2, HH, invP);

    // GEMM3: relu(bn2(h))[P,512] @ w2^T -> o[P,128]  (+ fused stats3)
    dgemm_kernel<HH, CC, true><<<dim3(PP / 128, 1), 256, 0, stream>>>(
        h_bf, w2_b, b2, act2, o_bf, stats3);
    finalize_kernel<<<1, CC, 0, stream>>>(stats3, g2, be2, act3, CC, invP);

    // out = bn3(o) + relu(bn1(y)), back to [B,C,N]
    final_kernel<<<dim3(NN / 32, BB), 256, 0, stream>>>(y_bf, o_bf, act1, act3, out);
}

// Round 4
// 213.477 us; speedup vs baseline: 1.0091x; 1.0091x over previous
//
#include <hip/hip_runtime.h>
#include <hip/hip_bf16.h>
#include <cstddef>
#include <cstdint>

// Problem constants: B=2, C=128, N=32768, K=9, H=512
#define BB 2
#define CC 128
#define NN 32768
#define KNBR 9
#define HH 512
#define PP (BB * NN)          // 65536 points
#define TWO_C 256
#define EPSBN 1e-5f

typedef __attribute__((ext_vector_type(4))) float f32x4;
typedef __attribute__((ext_vector_type(8))) short s16x8;

__device__ __forceinline__ float bf2f(unsigned int u) {
    return __uint_as_float(u << 16);
}
__device__ __forceinline__ unsigned short f2bf(float f) {
    unsigned int u = __float_as_uint(f);
    u += 0x7fffu + ((u >> 16) & 1u);   // RNE
    return (unsigned short)(u >> 16);
}

// Fragment-linear layout for a [P][K] bf16 tensor:
//   F[p/16][k/32][lane][8],  lane = ((k>>3)&3)*16 + (p&15),  elem j = k&7
// A wave's 16x32 MFMA fragment tile = one contiguous 1024B block.

// ---------------------------------------------------------------------------
// x [B, C, N] fp32 -> xT [B*N, C] bf16 (row-major; feeds gather only)
__global__ __launch_bounds__(256) void transpose_kernel(
    const float* __restrict__ x, unsigned short* __restrict__ xT) {
    __shared__ float t[32][129];
    const int b = blockIdx.y;
    const int n0 = blockIdx.x * 32;
    const int tid = threadIdx.x;
    {
        const int tn = tid % 32;
        const int cq = tid / 32;
        for (int c = cq; c < CC; c += 8)
            t[tn][c] = x[((size_t)b * CC + c) * NN + n0 + tn];
    }
    __syncthreads();
    {
        const int ct = tid % 128;
        const int nq = tid / 128;
        for (int nl = nq; nl < 32; nl += 2)
            xT[((size_t)b * NN + n0 + nl) * CC + ct] = f2bf(t[nl][ct]);
    }
}

// ---------------------------------------------------------------------------
// Gather + max-relative -> feat in FRAGMENT layout [P/16][8][64][8].
// Block = 16 points, 256 threads: thread (pl, cg) owns channels c0..c0+3 of
// point p0+pl for each pass; its 8 interleaved feat values {x,rel}x4 form
// exactly one 16B fragment slot. Each wave writes one full 1KB tile.
__global__ __launch_bounds__(256) void gather_kernel(
    const unsigned short* __restrict__ xT, const int* __restrict__ ei,
    unsigned short* __restrict__ feat) {
    __shared__ int e0s[16 * KNBR], e1s[16 * KNBR];
    const int p0 = blockIdx.x * 16;
    const int b = p0 >> 15;
    const int n0 = p0 & (NN - 1);
    const int tid = threadIdx.x;
    for (int i = tid; i < 2 * 16 * KNBR; i += 256) {
        if (i < 16 * KNBR) e0s[i] = ei[((size_t)b * NN + n0) * KNBR + i];
        else e1s[i - 16 * KNBR] = ei[((size_t)(BB + b) * NN + n0) * KNBR + (i - 16 * KNBR)];
    }
    __syncthreads();
    const int pl = tid & 15, cg = tid >> 4;
    const unsigned short* xb = xT + (size_t)b * NN * CC;
    const int n = n0 + pl;
    const int* e0 = e0s + pl * KNBR;
    const int* e1 = e1s + pl * KNBR;
#pragma unroll
    for (int pass = 0; pass < 2; pass++) {
        const int c0 = pass * 64 + cg * 4;
        const uint2 xc = *(const uint2*)(xb + (size_t)n * CC + c0);
        float m0 = -INFINITY, m1 = -INFINITY, m2 = -INFINITY, m3 = -INFINITY;
#pragma unroll
        for (int k = 0; k < KNBR; k++) {
            const uint2 va = *(const uint2*)(xb + (size_t)e0[k] * CC + c0);
            const uint2 vb = *(const uint2*)(xb + (size_t)e1[k] * CC + c0);
            m0 = fmaxf(m0, bf2f(va.x & 0xffffu) - bf2f(vb.x & 0xffffu));
            m1 = fmaxf(m1, bf2f(va.x >> 16) - bf2f(vb.x >> 16));
            m2 = fmaxf(m2, bf2f(va.y & 0xffffu) - bf2f(vb.y & 0xffffu));
            m3 = fmaxf(m3, bf2f(va.y >> 16) - bf2f(vb.y >> 16));
        }
        s16x8 o;
        o[0] = (short)(xc.x & 0xffffu);  o[1] = (short)f2bf(m0);
        o[2] = (short)(xc.x >> 16);      o[3] = (short)f2bf(m1);
        o[4] = (short)(xc.y & 0xffffu);  o[5] = (short)f2bf(m2);
        o[6] = (short)(xc.y >> 16);      o[7] = (short)f2bf(m3);
        // feat k-range = pass*128 + cg*8 -> ktile = pass*4 + (cg>>2), lane = (cg&3)*16+pl
        const size_t off =
            ((size_t)((p0 >> 4) * 8 + pass * 4 + (cg >> 2)) * 64 + ((cg & 3) * 16 + pl)) * 8;
        *(s16x8*)(feat + off) = o;
    }
}

// ---------------------------------------------------------------------------
// fp32 weights -> bf16 fragment layout. One thread per 16B slot.
// slots: w1 (OC=512,K=128): 8192; w2 (OC=128,K=512): 8192; w_mr (128,256): 4096
__global__ __launch_bounds__(256) void wconv_kernel(
    const float* __restrict__ w_mr, const float* __restrict__ w1,
    const float* __restrict__ w2, unsigned short* __restrict__ o_mr,
    unsigned short* __restrict__ o1, unsigned short* __restrict__ o2) {
    const int t = blockIdx.x * 256 + threadIdx.x;
    const float* src; unsigned short* dst; int K; int slot;
    if (t < 8192) { src = w1; dst = o1; K = 128; slot = t; }
    else if (t < 16384) { src = w2; dst = o2; K = 512; slot = t - 8192; }
    else if (t < 20480) { src = w_mr; dst = o_mr; K = 256; slot = t - 16384; }
    else return;
    const int lane = slot & 63;
    const int kt = (slot >> 6) % (K / 32);
    const int ot = (slot >> 6) / (K / 32);
    const int oc = ot * 16 + (lane & 15);
    const int k0 = kt * 32 + (lane >> 4) * 8;
    s16x8 v;
#pragma unroll
    for (int j = 0; j < 8; j++) v[j] = (short)f2bf(src[(size_t)oc * K + k0 + j]);
    *(s16x8*)(dst + (size_t)slot * 8) = v;
}

// ---------------------------------------------------------------------------
// Streaming fragment GEMM: zero LDS staging, zero main-loop barriers.
// A [P][KTOT] and W [OC][KTOT] both in fragment layout; every fragment load
// is one contiguous 1024B wave-load. actA fused in regs; stats fused in
// epilogue; C written in the CONSUMER's fragment layout (2B scalar stores,
// line-merged in L2 since all writers of a line are in one wave).
template <int KTOT, int OC, bool ACT>
__global__ __launch_bounds__(256) void fgemm_kernel(
    const unsigned short* __restrict__ A,
    const unsigned short* __restrict__ W,
    const float* __restrict__ bias,
    const float* __restrict__ act,      // [2*KTOT]: a then b
    unsigned short* __restrict__ Cout,  // fragment layout [P/16][OC/32][64][8]
    float* __restrict__ stats) {
    constexpr int KT = KTOT / 32;
    constexpr int OCT = OC / 32;
    __shared__ float bsA[256], bsB[256];

    const int tid = threadIdx.x;
    const int pb = blockIdx.x * 128;
    const int ob = blockIdx.y * 128;
    const int w = tid >> 6, wr = w >> 1, wc = w & 1;
    const int lane = tid & 63;
    const int lm = lane & 15, lg = lane >> 4;

    const unsigned short* Abase =
        A + ((size_t)((pb >> 4) + wr * 4) * KT * 64 + lane) * 8;
    const unsigned short* Wbase =
        W + ((size_t)((ob >> 4) + wc * 4) * KT * 64 + lane) * 8;

    f32x4 acc[4][4] = {};

    for (int kt = 0; kt < KT; kt++) {
        s16x8 aF[4], bF[4];
#pragma unroll
        for (int n = 0; n < 4; n++)
            bF[n] = *(const s16x8*)(Wbase + ((size_t)n * KT + kt) * 512);
        f32x4 sa0, sa1, sb0, sb1;
        if (ACT) {
            const int ke = kt * 32 + lg * 8;
            sa0 = *(const f32x4*)(act + ke);
            sa1 = *(const f32x4*)(act + ke + 4);
            sb0 = *(const f32x4*)(act + KTOT + ke);
            sb1 = *(const f32x4*)(act + KTOT + ke + 4);
        }
#pragma unroll
        for (int m = 0; m < 4; m++) {
            s16x8 v = *(const s16x8*)(Abase + ((size_t)m * KT + kt) * 512);
            if (ACT) {
                union { s16x8 s; __hip_bfloat162 h[4]; } u;
                u.s = v;
#pragma unroll
                for (int q = 0; q < 4; q++) {
                    const float2 f = __bfloat1622float2(u.h[q]);
                    const float slo = (q < 2) ? sa0[2 * q] : sa1[2 * q - 4];
                    const float shi = (q < 2) ? sa0[2 * q + 1] : sa1[2 * q - 3];
                    const float tlo = (q < 2) ? sb0[2 * q] : sb1[2 * q - 4];
                    const float thi = (q < 2) ? sb0[2 * q + 1] : sb1[2 * q - 3];
                    const float rlo = fmaxf(fmaf(slo, f.x, tlo), 0.f);
                    const float rhi = fmaxf(fmaf(shi, f.y, thi), 0.f);
                    u.h[q] = __float22bfloat162_rn(make_float2(rlo, rhi));
                }
                v = u.s;
            }
            aF[m] = v;
        }
#pragma unroll
        for (int m = 0; m < 4; m++)
#pragma unroll
            for (int n = 0; n < 4; n++)
                acc[m][n] = __builtin_amdgcn_mfma_f32_16x16x32_bf16(
                    aF[m], bF[n], acc[m][n], 0, 0, 0);
    }

    // ---- epilogue: bias, fragment-layout bf16 store, fused stats ----
    float sA[4] = {0.f, 0.f, 0.f, 0.f};
    float sB[4] = {0.f, 0.f, 0.f, 0.f};
#pragma unroll
    for (int n = 0; n < 4; n++) {
        const int o = ob + wc * 64 + n * 16 + lm;      // output channel
        const float bo = bias[o];
        const int kt_c = o >> 5;
        const int lgrp = ((o >> 3) & 3) * 16 + lg * 4; // lane base (j added below)
        const int jb = o & 7;
#pragma unroll
        for (int m = 0; m < 4; m++) {
            const int ptile = (pb >> 4) + wr * 4 + m;
            const size_t tbase = ((size_t)ptile * OCT + kt_c) * 512;
#pragma unroll
            for (int j = 0; j < 4; j++) {
                const float h = acc[m][n][j] + bo;
                Cout[tbase + (size_t)(lgrp + j) * 8 + jb] = f2bf(h);
                sA[n] += h;
                sB[n] = fmaf(h, h, sB[n]);
            }
        }
    }
#pragma unroll
    for (int n = 0; n < 4; n++) {
        float a = sA[n], q = sB[n];
        a += __shfl_xor(a, 16); a += __shfl_xor(a, 32);
        q += __shfl_xor(q, 16); q += __shfl_xor(q, 32);
        if (lg == 0) {
            bsA[wr * 128 + wc * 64 + n * 16 + lm] = a;
            bsB[wr * 128 + wc * 64 + n * 16 + lm] = q;
        }
    }
    __syncthreads();
    if (tid < 128) {
        atomicAdd(&stats[ob + tid], bsA[tid] + bsA[128 + tid]);
        atomicAdd(&stats[OC + ob + tid], bsB[tid] + bsB[128 + tid]);
    }
}

// ---------------------------------------------------------------------------
// stats -> per-channel affine (a, b): bn(v) = a*v + b
__global__ void finalize_kernel(const float* __restrict__ stats,
                                const float* __restrict__ g,
                                const float* __restrict__ be,
                                float* __restrict__ act, int CH, float invP) {
    const int c = blockIdx.x * blockDim.x + threadIdx.x;
    if (c < CH) {
        const float mean = stats[c] * invP;
        const float var = stats[CH + c] * invP - mean * mean;
        const float a = g[c] * rsqrtf(var + EPSBN);
        act[c] = a;
        act[CH + c] = be[c] - mean * a;
    }
}

// ---------------------------------------------------------------------------
// out[b,c,n] = a3*o + b3 + relu(a1*y + b1); reads y/o fragment tiles,
// LDS-transpose 32n x 128c, coalesced 128B-line writes to [B,C,N].
__global__ __launch_bounds__(256) void final_kernel(
    const unsigned short* __restrict__ yF, const unsigned short* __restrict__ oF,
    const float* __restrict__ act1, const float* __restrict__ act3,
    float* __restrict__ out) {
    __shared__ float t[32][132];
    const int p0 = blockIdx.x * 32;
    const int b = p0 >> 15;
    const int n0 = p0 & (NN - 1);
    const int tid = threadIdx.x;
#pragma unroll
    for (int s = tid; s < 512; s += 256) {
        const int pt = s >> 8;          // 0..1
        const int kt = (s >> 6) & 3;    // 32-channel tile
        const int lane = s & 63;
        const int nl = pt * 16 + (lane & 15);
        const int c0 = kt * 32 + (lane >> 4) * 8;
        const size_t off = ((size_t)(((p0 >> 4) + pt) * 4 + kt) * 64 + lane) * 8;
        const s16x8 yv = *(const s16x8*)(yF + off);
        const s16x8 ov = *(const s16x8*)(oF + off);
        const f32x4 a1lo = *(const f32x4*)(act1 + c0);
        const f32x4 a1hi = *(const f32x4*)(act1 + c0 + 4);
        const f32x4 b1lo = *(const f32x4*)(act1 + CC + c0);
        const f32x4 b1hi = *(const f32x4*)(act1 + CC + c0 + 4);
        const f32x4 a3lo = *(const f32x4*)(act3 + c0);
        const f32x4 a3hi = *(const f32x4*)(act3 + c0 + 4);
        const f32x4 b3lo = *(const f32x4*)(act3 + CC + c0);
        const f32x4 b3hi = *(const f32x4*)(act3 + CC + c0 + 4);
#pragma unroll
        for (int j = 0; j < 8; j++) {
            const float yf = bf2f((unsigned short)yv[j]);
            const float of = bf2f((unsigned short)ov[j]);
            const float a1 = (j < 4) ? a1lo[j] : a1hi[j - 4];
            const float b1 = (j < 4) ? b1lo[j] : b1hi[j - 4];
            const float a3 = (j < 4) ? a3lo[j] : a3hi[j - 4];
            const float b3 = (j < 4) ? b3lo[j] : b3hi[j - 4];
            t[nl][c0 + j] = fmaf(a3, of, b3) + fmaxf(fmaf(a1, yf, b1), 0.f);
        }
    }
    __syncthreads();
    const int tn = tid & 31;
    const int cq = tid >> 5;
    for (int c = cq; c < CC; c += 8)
        out[((size_t)b * CC + c) * NN + n0 + tn] = t[tn][c];
}

// ---------------------------------------------------------------------------
extern "C" void kernel_launch(void* const* d_in, const int* in_sizes, int n_in,
                              void* d_out, int out_size, void* d_ws, size_t ws_size,
                              hipStream_t stream) {
    const float* x     = (const float*)d_in[0];
    const int*   ei    = (const int*)d_in[1];
    const float* w_mr  = (const float*)d_in[2];
    const float* b_mr  = (const float*)d_in[3];
    const float* g_mr  = (const float*)d_in[4];
    const float* be_mr = (const float*)d_in[5];
    const float* w1    = (const float*)d_in[6];
    const float* b1    = (const float*)d_in[7];
    const float* g1    = (const float*)d_in[8];
    const float* be1   = (const float*)d_in[9];
    const float* w2    = (const float*)d_in[10];
    const float* b2    = (const float*)d_in[11];
    const float* g2    = (const float*)d_in[12];
    const float* be2   = (const float*)d_in[13];
    float* out = (float*)d_out;

    // workspace layout (bytes)
    char* ws = (char*)d_ws;
    unsigned short* xT    = (unsigned short*)(ws + 0);           // 16 MB row-major
    unsigned short* featF = (unsigned short*)(ws + 16777216);    // 32 MB frag
    unsigned short* yF    = (unsigned short*)(ws + 50331648);    // 16 MB frag
    unsigned short* hF    = (unsigned short*)(ws + 67108864);    // 64 MB frag
    unsigned short* oF    = (unsigned short*)(ws + 134217728);   // 16 MB frag
    unsigned short* wmrF  = (unsigned short*)(ws + 150994944);   // 64 KB frag
    unsigned short* w1F   = (unsigned short*)(ws + 151060480);   // 128 KB frag
    unsigned short* w2F   = (unsigned short*)(ws + 151191552);   // 128 KB frag
    float* stats1 = (float*)(ws + 151322624);                    // 2*128
    float* stats2 = (float*)(ws + 151323648);                    // 2*512
    float* stats3 = (float*)(ws + 151327744);                    // 2*128
    float* act1   = (float*)(ws + 151328768);                    // 2*128
    float* act2   = (float*)(ws + 151329792);                    // 2*512
    float* act3   = (float*)(ws + 151333888);                    // 2*128

    const float invP = 1.0f / (float)PP;

    hipMemsetAsync(stats1, 0, 6144, stream);   // zero all three stats arrays

    transpose_kernel<<<dim3(NN / 32, BB), 256, 0, stream>>>(x, xT);
    gather_kernel<<<PP / 16, 256, 0, stream>>>(xT, ei, featF);
    wconv_kernel<<<80, 256, 0, stream>>>(w_mr, w1, w2, wmrF, w1F, w2F);

    // GEMM1: feat[P,256] @ w_mr^T -> y[P,128]  (+ stats1)
    fgemm_kernel<TWO_C, CC, false><<<dim3(PP / 128, 1), 256, 0, stream>>>(
        featF, wmrF, b_mr, act1, yF, stats1);
    finalize_kernel<<<1, CC, 0, stream>>>(stats1, g_mr, be_mr, act1, CC, invP);

    // GEMM2: relu(bn1(y))[P,128] @ w1^T -> h[P,512]  (+ stats2)
    fgemm_kernel<CC, HH, true><<<dim3(PP / 128, HH / 128), 256, 0, stream>>>(
        yF, w1F, b1, act1, hF, stats2);
    finalize_kernel<<<1, HH, 0, stream>>>(stats2, g1, be1, act2, HH, invP);

    // GEMM3: relu(bn2(h))[P,512] @ w2^T -> o[P,128]  (+ stats3)
    fgemm_kernel<HH, CC, true><<<dim3(PP / 128, 1), 256, 0, stream>>>(
        hF, w2F, b2, act2, oF, stats3);
    finalize_kernel<<<1, CC, 0, stream>>>(stats3, g2, be2, act3, CC, invP);

    // out = bn3(o) + relu(bn1(y)), back to [B,C,N]
    final_kernel<<<PP / 32, 256, 0, stream>>>(yF, oF, act1, act3, out);
}

// Round 5
// 176.677 us; speedup vs baseline: 1.2192x; 1.2083x over previous
//
#include <hip/hip_runtime.h>
#include <hip/hip_bf16.h>
#include <cstddef>
#include <cstdint>

// Problem constants: B=2, C=128, N=32768, K=9, H=512
#define BB 2
#define CC 128
#define NN 32768
#define KNBR 9
#define HH 512
#define PP (BB * NN)          // 65536 points
#define TWO_C 256
#define EPSBN 1e-5f

typedef __attribute__((ext_vector_type(4))) float f32x4;
typedef __attribute__((ext_vector_type(8))) short s16x8;

__device__ __forceinline__ float bf2f(unsigned int u) {
    return __uint_as_float(u << 16);
}
__device__ __forceinline__ unsigned short f2bf(float f) {
    unsigned int u = __float_as_uint(f);
    u += 0x7fffu + ((u >> 16) & 1u);   // RNE
    return (unsigned short)(u >> 16);
}

// Fragment-linear layout for a [P][K] bf16 tensor:
//   F[p/16][k/32][lane][8],  lane = ((k>>3)&3)*16 + (p&15),  elem j = k&7
// A wave's 16x32 MFMA fragment tile = one contiguous 1024B block.

// ---------------------------------------------------------------------------
// x [B, C, N] fp32 -> xT [B*N, C] bf16 (row-major; feeds gather only)
__global__ __launch_bounds__(256) void transpose_kernel(
    const float* __restrict__ x, unsigned short* __restrict__ xT) {
    __shared__ float t[32][129];
    const int b = blockIdx.y;
    const int n0 = blockIdx.x * 32;
    const int tid = threadIdx.x;
    {
        const int tn = tid % 32;
        const int cq = tid / 32;
        for (int c = cq; c < CC; c += 8)
            t[tn][c] = x[((size_t)b * CC + c) * NN + n0 + tn];
    }
    __syncthreads();
    {
        const int ct = tid % 128;
        const int nq = tid / 128;
        for (int nl = nq; nl < 32; nl += 2)
            xT[((size_t)b * NN + n0 + nl) * CC + ct] = f2bf(t[nl][ct]);
    }
}

// ---------------------------------------------------------------------------
// Gather + max-relative -> feat in fragment layout.
// Phase 1 (R2-style): one wave per point, 64 lanes cover the full 256B row
// (lane owns channels 2l, 2l+1) -> full cache-line utilization on random
// rows. Result {x,rel} interleaved goes to LDS (padded rows, bank-floor).
// Phase 2: cooperative re-layout, 1KB coalesced fragment stores per wave.
__global__ __launch_bounds__(256) void gather_kernel(
    const unsigned short* __restrict__ xT, const int* __restrict__ ei,
    unsigned short* __restrict__ feat) {
    __shared__ unsigned short lds[16 * 264];   // 16 points x 256 k, +8 pad
    const int p0 = blockIdx.x * 16;
    const int b = p0 >> 15;
    const int n0 = p0 & (NN - 1);
    const int tid = threadIdx.x;
    const int wv = tid >> 6, lane = tid & 63;
    const unsigned short* xb = xT + (size_t)b * NN * CC;

#pragma unroll
    for (int q = 0; q < 4; q++) {
        const int pl = wv * 4 + q;
        const int n = n0 + pl;
        const int* e0 = ei + ((size_t)b * NN + n) * KNBR;         // x_j
        const int* e1 = ei + ((size_t)(BB + b) * NN + n) * KNBR;  // x_i
        const unsigned int xv = *(const unsigned int*)(xb + (size_t)n * CC + lane * 2);
        float m0 = -INFINITY, m1 = -INFINITY;
#pragma unroll
        for (int k = 0; k < KNBR; k++) {
            const int j0 = e0[k], j1 = e1[k];
            const unsigned int va = *(const unsigned int*)(xb + (size_t)j0 * CC + lane * 2);
            const unsigned int vb = *(const unsigned int*)(xb + (size_t)j1 * CC + lane * 2);
            m0 = fmaxf(m0, bf2f(va & 0xffffu) - bf2f(vb & 0xffffu));
            m1 = fmaxf(m1, bf2f(va >> 16) - bf2f(vb >> 16));
        }
        ushort4 o;
        o.x = (unsigned short)(xv & 0xffffu);   // k=4l   : x[2l]
        o.y = f2bf(m0);                         // k=4l+1 : rel[2l]
        o.z = (unsigned short)(xv >> 16);       // k=4l+2 : x[2l+1]
        o.w = f2bf(m1);                         // k=4l+3 : rel[2l+1]
        *(ushort4*)(lds + pl * 264 + lane * 4) = o;
    }
    __syncthreads();
#pragma unroll
    for (int pass = 0; pass < 2; pass++) {
        const int s = pass * 256 + tid;
        const int kt = s >> 6, ln = s & 63;
        const int pl = ln & 15, kq = ln >> 4;
        const s16x8 v = *(const s16x8*)(lds + pl * 264 + kt * 32 + kq * 8);
        *(s16x8*)(feat + ((size_t)((p0 >> 4) * 8 + kt) * 64 + ln) * 8) = v;
    }
}

// ---------------------------------------------------------------------------
// fp32 weights -> bf16 fragment layout. One thread per 16B slot.
__global__ __launch_bounds__(256) void wconv_kernel(
    const float* __restrict__ w_mr, const float* __restrict__ w1,
    const float* __restrict__ w2, unsigned short* __restrict__ o_mr,
    unsigned short* __restrict__ o1, unsigned short* __restrict__ o2) {
    const int t = blockIdx.x * 256 + threadIdx.x;
    const float* src; unsigned short* dst; int K; int slot;
    if (t < 8192) { src = w1; dst = o1; K = 128; slot = t; }
    else if (t < 16384) { src = w2; dst = o2; K = 512; slot = t - 8192; }
    else if (t < 20480) { src = w_mr; dst = o_mr; K = 256; slot = t - 16384; }
    else return;
    const int lane = slot & 63;
    const int kt = (slot >> 6) % (K / 32);
    const int ot = (slot >> 6) / (K / 32);
    const int oc = ot * 16 + (lane & 15);
    const int k0 = kt * 32 + (lane >> 4) * 8;
    s16x8 v;
#pragma unroll
    for (int j = 0; j < 8; j++) v[j] = (short)f2bf(src[(size_t)oc * K + k0 + j]);
    *(s16x8*)(dst + (size_t)slot * 8) = v;
}

// ---------------------------------------------------------------------------
// Streaming fragment GEMM: no LDS staging, no main-loop barriers; every
// fragment load is one contiguous 1024B wave-load. actA fused in regs.
// Epilogue: per-wave-private LDS transpose bounce -> coalesced 1KB fragment
// stores (replaces 64 scattered 2B global stores/wave). Stats fused.
template <int KTOT, int OC, bool ACT>
__global__ __launch_bounds__(256) void fgemm_kernel(
    const unsigned short* __restrict__ A,
    const unsigned short* __restrict__ W,
    const float* __restrict__ bias,
    const float* __restrict__ act,      // [2*KTOT]: a then b
    unsigned short* __restrict__ Cout,  // fragment layout [P/16][OC/32][64][8]
    float* __restrict__ stats) {
    constexpr int KT = KTOT / 32;
    constexpr int OCT = OC / 32;
    __shared__ unsigned short ctile[4][2][64][8];   // per-wave 2KB bounce
    __shared__ float bsA[256], bsB[256];

    const int tid = threadIdx.x;
    const int pb = blockIdx.x * 128;
    const int ob = blockIdx.y * 128;
    const int w = tid >> 6, wr = w >> 1, wc = w & 1;
    const int lane = tid & 63;
    const int lm = lane & 15, lg = lane >> 4;

    const unsigned short* Abase =
        A + ((size_t)((pb >> 4) + wr * 4) * KT * 64 + lane) * 8;
    const unsigned short* Wbase =
        W + ((size_t)((ob >> 4) + wc * 4) * KT * 64 + lane) * 8;

    f32x4 acc[4][4] = {};

    for (int kt = 0; kt < KT; kt++) {
        s16x8 aF[4], bF[4];
#pragma unroll
        for (int n = 0; n < 4; n++)
            bF[n] = *(const s16x8*)(Wbase + ((size_t)n * KT + kt) * 512);
        f32x4 sa0, sa1, sb0, sb1;
        if (ACT) {
            const int ke = kt * 32 + lg * 8;
            sa0 = *(const f32x4*)(act + ke);
            sa1 = *(const f32x4*)(act + ke + 4);
            sb0 = *(const f32x4*)(act + KTOT + ke);
            sb1 = *(const f32x4*)(act + KTOT + ke + 4);
        }
#pragma unroll
        for (int m = 0; m < 4; m++) {
            s16x8 v = *(const s16x8*)(Abase + ((size_t)m * KT + kt) * 512);
            if (ACT) {
                union { s16x8 s; __hip_bfloat162 h[4]; } u;
                u.s = v;
#pragma unroll
                for (int q = 0; q < 4; q++) {
                    const float2 f = __bfloat1622float2(u.h[q]);
                    const float slo = (q < 2) ? sa0[2 * q] : sa1[2 * q - 4];
                    const float shi = (q < 2) ? sa0[2 * q + 1] : sa1[2 * q - 3];
                    const float tlo = (q < 2) ? sb0[2 * q] : sb1[2 * q - 4];
                    const float thi = (q < 2) ? sb0[2 * q + 1] : sb1[2 * q - 3];
                    const float rlo = fmaxf(fmaf(slo, f.x, tlo), 0.f);
                    const float rhi = fmaxf(fmaf(shi, f.y, thi), 0.f);
                    u.h[q] = __float22bfloat162_rn(make_float2(rlo, rhi));
                }
                v = u.s;
            }
            aF[m] = v;
        }
#pragma unroll
        for (int m = 0; m < 4; m++)
#pragma unroll
            for (int n = 0; n < 4; n++)
                acc[m][n] = __builtin_amdgcn_mfma_f32_16x16x32_bf16(
                    aF[m], bF[n], acc[m][n], 0, 0, 0);
    }

    // ---- epilogue: bias, LDS transpose bounce, coalesced frag stores ----
    float sA[4] = {0.f, 0.f, 0.f, 0.f};
    float sB[4] = {0.f, 0.f, 0.f, 0.f};
    float bo[4];
#pragma unroll
    for (int n = 0; n < 4; n++) bo[n] = bias[ob + wc * 64 + n * 16 + lm];
    const int octile0 = (ob >> 5) + wc * 2;
    const int elem = lm & 7;
#pragma unroll
    for (int m = 0; m < 4; m++) {
#pragma unroll
        for (int n = 0; n < 4; n++) {
            const int tile = n >> 1;
            const int lbase = ((n & 1) * 2 + (lm >> 3)) * 16 + lg * 4;
#pragma unroll
            for (int j = 0; j < 4; j++) {
                const float h = acc[m][n][j] + bo[n];
                sA[n] += h;
                sB[n] = fmaf(h, h, sB[n]);
                ctile[w][tile][lbase + j][elem] = f2bf(h);
            }
        }
        // wave-private region: in-order DS ops, compiler inserts lgkmcnt
        const int ptile = (pb >> 4) + wr * 4 + m;
#pragma unroll
        for (int tile = 0; tile < 2; tile++) {
            const s16x8 v = *(const s16x8*)&ctile[w][tile][lane][0];
            *(s16x8*)(Cout + ((size_t)(ptile * OCT + octile0 + tile) * 64 + lane) * 8) = v;
        }
    }
#pragma unroll
    for (int n = 0; n < 4; n++) {
        float a = sA[n], q = sB[n];
        a += __shfl_xor(a, 16); a += __shfl_xor(a, 32);
        q += __shfl_xor(q, 16); q += __shfl_xor(q, 32);
        if (lg == 0) {
            bsA[wr * 128 + wc * 64 + n * 16 + lm] = a;
            bsB[wr * 128 + wc * 64 + n * 16 + lm] = q;
        }
    }
    __syncthreads();
    if (tid < 128) {
        atomicAdd(&stats[ob + tid], bsA[tid] + bsA[128 + tid]);
        atomicAdd(&stats[OC + ob + tid], bsB[tid] + bsB[128 + tid]);
    }
}

// ---------------------------------------------------------------------------
// stats -> per-channel affine (a, b): bn(v) = a*v + b
__global__ void finalize_kernel(const float* __restrict__ stats,
                                const float* __restrict__ g,
                                const float* __restrict__ be,
                                float* __restrict__ act, int CH, float invP) {
    const int c = blockIdx.x * blockDim.x + threadIdx.x;
    if (c < CH) {
        const float mean = stats[c] * invP;
        const float var = stats[CH + c] * invP - mean * mean;
        const float a = g[c] * rsqrtf(var + EPSBN);
        act[c] = a;
        act[CH + c] = be[c] - mean * a;
    }
}

// ---------------------------------------------------------------------------
// out[b,c,n] = a3*o + b3 + relu(a1*y + b1); reads y/o fragment tiles,
// LDS-transpose 32n x 128c, coalesced 128B-line writes to [B,C,N].
__global__ __launch_bounds__(256) void final_kernel(
    const unsigned short* __restrict__ yF, const unsigned short* __restrict__ oF,
    const float* __restrict__ act1, const float* __restrict__ act3,
    float* __restrict__ out) {
    __shared__ float t[32][132];
    const int p0 = blockIdx.x * 32;
    const int b = p0 >> 15;
    const int n0 = p0 & (NN - 1);
    const int tid = threadIdx.x;
#pragma unroll
    for (int s = tid; s < 512; s += 256) {
        const int pt = s >> 8;          // 0..1
        const int kt = (s >> 6) & 3;    // 32-channel tile
        const int lane = s & 63;
        const int nl = pt * 16 + (lane & 15);
        const int c0 = kt * 32 + (lane >> 4) * 8;
        const size_t off = ((size_t)(((p0 >> 4) + pt) * 4 + kt) * 64 + lane) * 8;
        const s16x8 yv = *(const s16x8*)(yF + off);
        const s16x8 ov = *(const s16x8*)(oF + off);
        const f32x4 a1lo = *(const f32x4*)(act1 + c0);
        const f32x4 a1hi = *(const f32x4*)(act1 + c0 + 4);
        const f32x4 b1lo = *(const f32x4*)(act1 + CC + c0);
        const f32x4 b1hi = *(const f32x4*)(act1 + CC + c0 + 4);
        const f32x4 a3lo = *(const f32x4*)(act3 + c0);
        const f32x4 a3hi = *(const f32x4*)(act3 + c0 + 4);
        const f32x4 b3lo = *(const f32x4*)(act3 + CC + c0);
        const f32x4 b3hi = *(const f32x4*)(act3 + CC + c0 + 4);
#pragma unroll
        for (int j = 0; j < 8; j++) {
            const float yf = bf2f((unsigned short)yv[j]);
            const float of = bf2f((unsigned short)ov[j]);
            const float a1 = (j < 4) ? a1lo[j] : a1hi[j - 4];
            const float b1 = (j < 4) ? b1lo[j] : b1hi[j - 4];
            const float a3 = (j < 4) ? a3lo[j] : a3hi[j - 4];
            const float b3 = (j < 4) ? b3lo[j] : b3hi[j - 4];
            t[nl][c0 + j] = fmaf(a3, of, b3) + fmaxf(fmaf(a1, yf, b1), 0.f);
        }
    }
    __syncthreads();
    const int tn = tid & 31;
    const int cq = tid >> 5;
    for (int c = cq; c < CC; c += 8)
        out[((size_t)b * CC + c) * NN + n0 + tn] = t[tn][c];
}

// ---------------------------------------------------------------------------
extern "C" void kernel_launch(void* const* d_in, const int* in_sizes, int n_in,
                              void* d_out, int out_size, void* d_ws, size_t ws_size,
                              hipStream_t stream) {
    const float* x     = (const float*)d_in[0];
    const int*   ei    = (const int*)d_in[1];
    const float* w_mr  = (const float*)d_in[2];
    const float* b_mr  = (const float*)d_in[3];
    const float* g_mr  = (const float*)d_in[4];
    const float* be_mr = (const float*)d_in[5];
    const float* w1    = (const float*)d_in[6];
    const float* b1    = (const float*)d_in[7];
    const float* g1    = (const float*)d_in[8];
    const float* be1   = (const float*)d_in[9];
    const float* w2    = (const float*)d_in[10];
    const float* b2    = (const float*)d_in[11];
    const float* g2    = (const float*)d_in[12];
    const float* be2   = (const float*)d_in[13];
    float* out = (float*)d_out;

    // workspace layout (bytes)
    char* ws = (char*)d_ws;
    unsigned short* xT    = (unsigned short*)(ws + 0);           // 16 MB row-major
    unsigned short* featF = (unsigned short*)(ws + 16777216);    // 32 MB frag
    unsigned short* yF    = (unsigned short*)(ws + 50331648);    // 16 MB frag
    unsigned short* hF    = (unsigned short*)(ws + 67108864);    // 64 MB frag
    unsigned short* oF    = (unsigned short*)(ws + 134217728);   // 16 MB frag
    unsigned short* wmrF  = (unsigned short*)(ws + 150994944);   // 64 KB frag
    unsigned short* w1F   = (unsigned short*)(ws + 151060480);   // 128 KB frag
    unsigned short* w2F   = (unsigned short*)(ws + 151191552);   // 128 KB frag
    float* stats1 = (float*)(ws + 151322624);                    // 2*128
    float* stats2 = (float*)(ws + 151323648);                    // 2*512
    float* stats3 = (float*)(ws + 151327744);                    // 2*128
    float* act1   = (float*)(ws + 151328768);                    // 2*128
    float* act2   = (float*)(ws + 151329792);                    // 2*512
    float* act3   = (float*)(ws + 151333888);                    // 2*128

    const float invP = 1.0f / (float)PP;

    hipMemsetAsync(stats1, 0, 6144, stream);   // zero all three stats arrays

    transpose_kernel<<<dim3(NN / 32, BB), 256, 0, stream>>>(x, xT);
    gather_kernel<<<PP / 16, 256, 0, stream>>>(xT, ei, featF);
    wconv_kernel<<<80, 256, 0, stream>>>(w_mr, w1, w2, wmrF, w1F, w2F);

    // GEMM1: feat[P,256] @ w_mr^T -> y[P,128]  (+ stats1)
    fgemm_kernel<TWO_C, CC, false><<<dim3(PP / 128, 1), 256, 0, stream>>>(
        featF, wmrF, b_mr, act1, yF, stats1);
    finalize_kernel<<<1, CC, 0, stream>>>(stats1, g_mr, be_mr, act1, CC, invP);

    // GEMM2: relu(bn1(y))[P,128] @ w1^T -> h[P,512]  (+ stats2)
    fgemm_kernel<CC, HH, true><<<dim3(PP / 128, HH / 128), 256, 0, stream>>>(
        yF, w1F, b1, act1, hF, stats2);
    finalize_kernel<<<1, HH, 0, stream>>>(stats2, g1, be1, act2, HH, invP);

    // GEMM3: relu(bn2(h))[P,512] @ w2^T -> o[P,128]  (+ stats3)
    fgemm_kernel<HH, CC, true><<<dim3(PP / 128, 1), 256, 0, stream>>>(
        hF, w2F, b2, act2, oF, stats3);
    finalize_kernel<<<1, CC, 0, stream>>>(stats3, g2, be2, act3, CC, invP);

    // out = bn3(o) + relu(bn1(y)), back to [B,C,N]
    final_kernel<<<PP / 32, 256, 0, stream>>>(yF, oF, act1, act3, out);
}